// Round 5
// baseline (329.523 us; speedup 1.0000x reference)
//
#include <hip/hip_runtime.h>

// D = H = W = 128, NUM_STEPS = 7 (MONAI DVF2DDF scaling-and-squaring)
#define DD 128
constexpr int NV = DD * DD * DD;           // 2,097,152 voxels
constexpr float SCALE = 1.0f / 128.0f;     // 2^-NUM_STEPS

// LDS tile geometry for the integration steps.
// Halo=2 covers gather displacement |disp| < 2. Bound: |field_k| <= 2^k*|dvf|/128;
// steps 1..6 gather with |field_5| <= max|dvf|/4 < 2 for any sane input; a
// per-lane global fallback keeps ANY input correct.
#define TZ 8
#define TY 8
#define TX 32
#define HALO 2
#define SZ (TZ + 2 * HALO)      // 12
#define SY (TY + 2 * HALO)      // 12
#define SX (TX + 2 * HALO)      // 36
#define SVOX (SZ * SY * SX)     // 5184  (3 float planes = 62 KB LDS)

__device__ __forceinline__ float clampc(float v) {
    return fminf(fmaxf(v, 0.0f), (float)(DD - 1));
}

// ----- component-wise corner info (for LDS-local or global indexing) -----
struct CornerC {
    int z0, z1, y0, y1, x0, x1;
    float w000, w001, w010, w011, w100, w101, w110, w111;
};

__device__ __forceinline__ CornerC corner_setup_c(float cz, float cy, float cx) {
    float z0f = floorf(cz), y0f = floorf(cy), x0f = floorf(cx);
    float wz = cz - z0f, wy = cy - y0f, wx = cx - x0f;
    CornerC c;
    c.z0 = (int)z0f; c.y0 = (int)y0f; c.x0 = (int)x0f;
    c.z1 = min(c.z0 + 1, DD - 1);
    c.y1 = min(c.y0 + 1, DD - 1);
    c.x1 = min(c.x0 + 1, DD - 1);
    float omz = 1.0f - wz, omy = 1.0f - wy, omx = 1.0f - wx;
    c.w000 = omz * omy * omx; c.w001 = omz * omy * wx;
    c.w010 = omz * wy * omx;  c.w011 = omz * wy * wx;
    c.w100 = wz * omy * omx;  c.w101 = wz * omy * wx;
    c.w110 = wz * wy * omx;   c.w111 = wz * wy * wx;
    return c;
}

// ----- linear-index corner info (global gathers) -----
struct Corners {
    int i000, i001, i010, i011, i100, i101, i110, i111;
    float w000, w001, w010, w011, w100, w101, w110, w111;
};

__device__ __forceinline__ Corners corner_setup(float cz, float cy, float cx) {
    CornerC c = corner_setup_c(cz, cy, cx);
    Corners g;
    int zs0 = c.z0 << 14, zs1 = c.z1 << 14;
    int ys0 = c.y0 << 7,  ys1 = c.y1 << 7;
    g.i000 = zs0 + ys0 + c.x0; g.i001 = zs0 + ys0 + c.x1;
    g.i010 = zs0 + ys1 + c.x0; g.i011 = zs0 + ys1 + c.x1;
    g.i100 = zs1 + ys0 + c.x0; g.i101 = zs1 + ys0 + c.x1;
    g.i110 = zs1 + ys1 + c.x0; g.i111 = zs1 + ys1 + c.x1;
    g.w000 = c.w000; g.w001 = c.w001; g.w010 = c.w010; g.w011 = c.w011;
    g.w100 = c.w100; g.w101 = c.w101; g.w110 = c.w110; g.w111 = c.w111;
    return g;
}

__device__ __forceinline__ float3 trilerp4(const float4* __restrict__ src,
                                           const Corners& c, float3 base) {
    float4 v000 = src[c.i000], v001 = src[c.i001];
    float4 v010 = src[c.i010], v011 = src[c.i011];
    float4 v100 = src[c.i100], v101 = src[c.i101];
    float4 v110 = src[c.i110], v111 = src[c.i111];
    float3 r;
    r.x = base.x + c.w000*v000.x + c.w001*v001.x + c.w010*v010.x + c.w011*v011.x
                 + c.w100*v100.x + c.w101*v101.x + c.w110*v110.x + c.w111*v111.x;
    r.y = base.y + c.w000*v000.y + c.w001*v001.y + c.w010*v010.y + c.w011*v011.y
                 + c.w100*v100.y + c.w101*v101.y + c.w110*v110.y + c.w111*v111.y;
    r.z = base.z + c.w000*v000.z + c.w001*v001.z + c.w010*v010.z + c.w011*v011.z
                 + c.w100*v100.z + c.w101*v101.z + c.w110*v110.z + c.w111*v111.z;
    return r;
}

// ===========================================================================
// FAST PATH
// ===========================================================================

// pack: planar dvf [3,DHW] (coalesced reads) -> float4 field, scaled 2^-7
__global__ __launch_bounds__(256)
void pack_kernel(const float* __restrict__ dvf, float4* __restrict__ dst) {
    int tid = blockIdx.x * blockDim.x + threadIdx.x;
    float4 v;
    v.x = dvf[tid] * SCALE;
    v.y = dvf[tid + NV] * SCALE;
    v.z = dvf[tid + 2 * NV] * SCALE;
    v.w = 0.0f;
    dst[tid] = v;
}

// LDS-staged step: block = 8z x 8y x 32x tile; coalesced stage of tile+halo
// into 3 SoA LDS planes, then all 8 corner gathers served from LDS.
__global__ __launch_bounds__(256)
void step_lds_kernel(const float4* __restrict__ src, float4* __restrict__ dst) {
    __shared__ float sf0[SVOX];
    __shared__ float sf1[SVOX];
    __shared__ float sf2[SVOX];

    int bid = blockIdx.x;                  // 1024 blocks = 4x * 16y * 16z tiles
    int X0 = (bid & 3) * TX;
    int Y0 = ((bid >> 2) & 15) * TY;
    int Z0 = (bid >> 6) * TZ;
    int t = threadIdx.x;

    // ---- stage tile + halo (clamped at volume edges; dup entries unused) ----
    for (int s = t; s < SVOX; s += 256) {
        int xp = s % SX;
        int r  = s / SX;
        int yp = r % SY;
        int zp = r / SY;
        int gz = min(max(Z0 - HALO + zp, 0), DD - 1);
        int gy = min(max(Y0 - HALO + yp, 0), DD - 1);
        int gx = min(max(X0 - HALO + xp, 0), DD - 1);
        float4 v = src[(gz << 14) + (gy << 7) + gx];
        sf0[s] = v.x; sf1[s] = v.y; sf2[s] = v.z;
    }
    __syncthreads();

    int tx = t & (TX - 1);
    int ty = t >> 5;                        // 0..7
    int x = X0 + tx, y = Y0 + ty;

    for (int lz = 0; lz < TZ; ++lz) {
        int z = Z0 + lz;
        int sown = ((lz + HALO) * SY + (ty + HALO)) * SX + (tx + HALO);
        float d0 = sf0[sown], d1 = sf1[sown], d2 = sf2[sown];

        float cz = clampc((float)z + d0);
        float cy = clampc((float)y + d1);
        float cx = clampc((float)x + d2);
        CornerC c = corner_setup_c(cz, cy, cx);

        int lz0 = c.z0 - (Z0 - HALO), lz1 = c.z1 - (Z0 - HALO);
        int ly0 = c.y0 - (Y0 - HALO), ly1 = c.y1 - (Y0 - HALO);
        int lx0 = c.x0 - (X0 - HALO), lx1 = c.x1 - (X0 - HALO);
        bool in_tile = (lz0 >= 0) & (lz1 < SZ) & (ly0 >= 0) & (ly1 < SY)
                     & (lx0 >= 0) & (lx1 < SX);

        float r0, r1, r2;
        if (__builtin_expect(in_tile, 1)) {
            int b00 = (lz0 * SY + ly0) * SX;
            int b01 = (lz0 * SY + ly1) * SX;
            int b10 = (lz1 * SY + ly0) * SX;
            int b11 = (lz1 * SY + ly1) * SX;
            int a000 = b00 + lx0, a001 = b00 + lx1;
            int a010 = b01 + lx0, a011 = b01 + lx1;
            int a100 = b10 + lx0, a101 = b10 + lx1;
            int a110 = b11 + lx0, a111 = b11 + lx1;
            r0 = c.w000*sf0[a000] + c.w001*sf0[a001] + c.w010*sf0[a010] + c.w011*sf0[a011]
               + c.w100*sf0[a100] + c.w101*sf0[a101] + c.w110*sf0[a110] + c.w111*sf0[a111];
            r1 = c.w000*sf1[a000] + c.w001*sf1[a001] + c.w010*sf1[a010] + c.w011*sf1[a011]
               + c.w100*sf1[a100] + c.w101*sf1[a101] + c.w110*sf1[a110] + c.w111*sf1[a111];
            r2 = c.w000*sf2[a000] + c.w001*sf2[a001] + c.w010*sf2[a010] + c.w011*sf2[a011]
               + c.w100*sf2[a100] + c.w101*sf2[a101] + c.w110*sf2[a110] + c.w111*sf2[a111];
        } else {
            // rare (never for sane inputs): global gather keeps any input correct
            int zs0 = c.z0 << 14, zs1 = c.z1 << 14;
            int ys0 = c.y0 << 7,  ys1 = c.y1 << 7;
            float4 v000 = src[zs0 + ys0 + c.x0], v001 = src[zs0 + ys0 + c.x1];
            float4 v010 = src[zs0 + ys1 + c.x0], v011 = src[zs0 + ys1 + c.x1];
            float4 v100 = src[zs1 + ys0 + c.x0], v101 = src[zs1 + ys0 + c.x1];
            float4 v110 = src[zs1 + ys1 + c.x0], v111 = src[zs1 + ys1 + c.x1];
            r0 = c.w000*v000.x + c.w001*v001.x + c.w010*v010.x + c.w011*v011.x
               + c.w100*v100.x + c.w101*v101.x + c.w110*v110.x + c.w111*v111.x;
            r1 = c.w000*v000.y + c.w001*v001.y + c.w010*v010.y + c.w011*v011.y
               + c.w100*v100.y + c.w101*v101.y + c.w110*v110.y + c.w111*v111.y;
            r2 = c.w000*v000.z + c.w001*v001.z + c.w010*v010.z + c.w011*v011.z
               + c.w100*v100.z + c.w101*v101.z + c.w110*v110.z + c.w111*v111.z;
        }

        dst[(z << 14) + (y << 7) + x] = make_float4(d0 + r0, d1 + r1, d2 + r2, 0.0f);
    }
}

// step 7 fused with output warps AND dvf pass-through (unchanged from R4)
__global__ __launch_bounds__(256)
void step7_final4_kernel(const float4* __restrict__ src,
                         const float* __restrict__ mimg,
                         const float* __restrict__ mlab,
                         const float* __restrict__ dvf,
                         float* __restrict__ ddf_out,
                         float* __restrict__ pred_img,
                         float* __restrict__ pred_lab,
                         float* __restrict__ dvf_out) {
    int tid = blockIdx.x * blockDim.x + threadIdx.x;
    int x = tid & (DD - 1);
    int y = (tid >> 7) & (DD - 1);
    int z = tid >> 14;

    float4 s = src[tid];
    float dv0 = dvf[tid], dv1 = dvf[tid + NV], dv2 = dvf[tid + 2 * NV];

    Corners c = corner_setup(clampc((float)z + s.x),
                             clampc((float)y + s.y),
                             clampc((float)x + s.z));
    float3 r = trilerp4(src, c, make_float3(s.x, s.y, s.z));

    ddf_out[tid]          = r.x;
    ddf_out[tid + NV]     = r.y;
    ddf_out[tid + 2 * NV] = r.z;
    dvf_out[tid]          = dv0;
    dvf_out[tid + NV]     = dv1;
    dvf_out[tid + 2 * NV] = dv2;

    float cz = clampc((float)z + r.x);
    float cy = clampc((float)y + r.y);
    float cx = clampc((float)x + r.z);

    {   // bilinear warp of moving_image
        Corners g = corner_setup(cz, cy, cx);
        pred_img[tid] = g.w000*mimg[g.i000] + g.w001*mimg[g.i001]
                      + g.w010*mimg[g.i010] + g.w011*mimg[g.i011]
                      + g.w100*mimg[g.i100] + g.w101*mimg[g.i101]
                      + g.w110*mimg[g.i110] + g.w111*mimg[g.i111];
    }
    {   // nearest warp of moving_label (jnp.round = ties-to-even = rintf)
        int zi = (int)rintf(cz);
        int yi = (int)rintf(cy);
        int xi = (int)rintf(cx);
        pred_lab[tid] = mlab[(zi << 14) + (yi << 7) + xi];
    }
}

// ===========================================================================
// FALLBACK PATH (ws too small): float3 ping-pong inside d_out
// ===========================================================================

__device__ __forceinline__ void trilerp3i(const float* __restrict__ src,
                                          const Corners& c,
                                          float& r0, float& r1, float& r2) {
    const float* p000 = src + 3 * c.i000; const float* p001 = src + 3 * c.i001;
    const float* p010 = src + 3 * c.i010; const float* p011 = src + 3 * c.i011;
    const float* p100 = src + 3 * c.i100; const float* p101 = src + 3 * c.i101;
    const float* p110 = src + 3 * c.i110; const float* p111 = src + 3 * c.i111;
    r0 = c.w000*p000[0] + c.w001*p001[0] + c.w010*p010[0] + c.w011*p011[0]
       + c.w100*p100[0] + c.w101*p101[0] + c.w110*p110[0] + c.w111*p111[0];
    r1 = c.w000*p000[1] + c.w001*p001[1] + c.w010*p010[1] + c.w011*p011[1]
       + c.w100*p100[1] + c.w101*p101[1] + c.w110*p110[1] + c.w111*p111[1];
    r2 = c.w000*p000[2] + c.w001*p001[2] + c.w010*p010[2] + c.w011*p011[2]
       + c.w100*p100[2] + c.w101*p101[2] + c.w110*p110[2] + c.w111*p111[2];
}

__global__ __launch_bounds__(256)
void init3_kernel(const float* __restrict__ dvf, float* __restrict__ A) {
    int tid = blockIdx.x * blockDim.x + threadIdx.x;
    float* p = A + 3 * tid;
    p[0] = dvf[tid] * SCALE;
    p[1] = dvf[tid + NV] * SCALE;
    p[2] = dvf[tid + 2 * NV] * SCALE;
}

__global__ __launch_bounds__(256)
void step3_kernel(const float* __restrict__ src, float* __restrict__ dst) {
    int tid = blockIdx.x * blockDim.x + threadIdx.x;
    int x = tid & (DD - 1);
    int y = (tid >> 7) & (DD - 1);
    int z = tid >> 14;
    const float* s = src + 3 * tid;
    float d0 = s[0], d1 = s[1], d2 = s[2];
    Corners c = corner_setup(clampc((float)z + d0),
                             clampc((float)y + d1),
                             clampc((float)x + d2));
    float r0, r1, r2;
    trilerp3i(src, c, r0, r1, r2);
    float* p = dst + 3 * tid;
    p[0] = d0 + r0; p[1] = d1 + r1; p[2] = d2 + r2;
}

__global__ __launch_bounds__(256)
void step7_final3_kernel(const float* __restrict__ src,
                         const float* __restrict__ mimg,
                         const float* __restrict__ mlab,
                         const float* __restrict__ dvf,
                         float* __restrict__ ddf_out,
                         float* __restrict__ pred_img,
                         float* __restrict__ pred_lab,
                         float* __restrict__ dvf_out) {
    int tid = blockIdx.x * blockDim.x + threadIdx.x;
    int x = tid & (DD - 1);
    int y = (tid >> 7) & (DD - 1);
    int z = tid >> 14;
    const float* s = src + 3 * tid;
    float d0 = s[0], d1 = s[1], d2 = s[2];
    Corners c = corner_setup(clampc((float)z + d0),
                             clampc((float)y + d1),
                             clampc((float)x + d2));
    float r0, r1, r2;
    trilerp3i(src, c, r0, r1, r2);
    r0 += d0; r1 += d1; r2 += d2;
    ddf_out[tid]          = r0;
    ddf_out[tid + NV]     = r1;
    ddf_out[tid + 2 * NV] = r2;
    dvf_out[tid]          = dvf[tid];
    dvf_out[tid + NV]     = dvf[tid + NV];
    dvf_out[tid + 2 * NV] = dvf[tid + 2 * NV];
    float cz = clampc((float)z + r0);
    float cy = clampc((float)y + r1);
    float cx = clampc((float)x + r2);
    {
        Corners g = corner_setup(cz, cy, cx);
        pred_img[tid] = g.w000*mimg[g.i000] + g.w001*mimg[g.i001]
                      + g.w010*mimg[g.i010] + g.w011*mimg[g.i011]
                      + g.w100*mimg[g.i100] + g.w101*mimg[g.i101]
                      + g.w110*mimg[g.i110] + g.w111*mimg[g.i111];
    }
    {
        int zi = (int)rintf(cz);
        int yi = (int)rintf(cy);
        int xi = (int)rintf(cx);
        pred_lab[tid] = mlab[(zi << 14) + (yi << 7) + xi];
    }
}

// ===========================================================================

extern "C" void kernel_launch(void* const* d_in, const int* in_sizes, int n_in,
                              void* d_out, int out_size, void* d_ws, size_t ws_size,
                              hipStream_t stream) {
    const float* dvf  = (const float*)d_in[0];
    const float* mimg = (const float*)d_in[1];
    // d_in[2] = fixed_image: unused by the reference outputs
    const float* mlab = (const float*)d_in[3];

    float* out      = (float*)d_out;
    float* ddf_out  = out;              // slot 0: ddf  [3,D,H,W]
    float* pred_img = out + 3 * NV;     // slot 1
    float* pred_lab = out + 4 * NV;     // slot 2
    float* dvf_out  = out + 5 * NV;     // slot 3: dvf pass-through

    dim3 block(256);
    dim3 grid(NV / 256);                // 8192 blocks
    dim3 gridT(NV / (TZ * TY * TX));    // 1024 tile blocks

    if (ws_size >= (size_t)NV * 4 * sizeof(float)) {
        // FAST PATH. Ping-pong: P = d_ws (32 MB), Q = out[4NV, 8NV) (32 MB).
        // Q is dead before step7_final writes over it (lab slot + dvf slot).
        float4* P = (float4*)d_ws;
        float4* Q = (float4*)(out + 4 * NV);

        pack_kernel<<<grid, block, 0, stream>>>(dvf, P);               // init -> P
        step_lds_kernel<<<gridT, block, 0, stream>>>(P, Q);            // step 1
        step_lds_kernel<<<gridT, block, 0, stream>>>(Q, P);            // step 2
        step_lds_kernel<<<gridT, block, 0, stream>>>(P, Q);            // step 3
        step_lds_kernel<<<gridT, block, 0, stream>>>(Q, P);            // step 4
        step_lds_kernel<<<gridT, block, 0, stream>>>(P, Q);            // step 5
        step_lds_kernel<<<gridT, block, 0, stream>>>(Q, P);            // step 6 -> P
        step7_final4_kernel<<<grid, block, 0, stream>>>(P, mimg, mlab, dvf,
                                                        ddf_out, pred_img,
                                                        pred_lab, dvf_out);
    } else {
        // FALLBACK: float3 ping-pong inside d_out.
        float* A = dvf_out;             // [5NV, 8NV)
        float* B = ddf_out;             // [0, 3NV)
        init3_kernel<<<grid, block, 0, stream>>>(dvf, A);
        step3_kernel<<<grid, block, 0, stream>>>(A, B);           // step 1
        step3_kernel<<<grid, block, 0, stream>>>(B, A);           // step 2
        step3_kernel<<<grid, block, 0, stream>>>(A, B);           // step 3
        step3_kernel<<<grid, block, 0, stream>>>(B, A);           // step 4
        step3_kernel<<<grid, block, 0, stream>>>(A, B);           // step 5
        step3_kernel<<<grid, block, 0, stream>>>(B, A);           // step 6 -> A
        step7_final3_kernel<<<grid, block, 0, stream>>>(A, mimg, mlab, dvf,
                                                        ddf_out, pred_img,
                                                        pred_lab, dvf_out);
    }
}

// Round 6
// 268.160 us; speedup vs baseline: 1.2288x; 1.2288x over previous
//
#include <hip/hip_runtime.h>

// D = H = W = 128, NUM_STEPS = 7 (MONAI DVF2DDF scaling-and-squaring)
#define DD 128
constexpr int NV = DD * DD * DD;           // 2,097,152 voxels
constexpr float SCALE = 1.0f / 128.0f;     // 2^-NUM_STEPS

// LDS tile for integration steps: 4z x 4y x 64x, halo 1.
// Halo-1 validity: gather displacement in step k is |field_{k-1}|;
// |field_k| <= 2^k * max|dvf|/128, max|dvf|~2.6 -> |field_5| <= 0.64 < 1.
// Out-of-tile corners (any input) take a per-lane global fallback.
#define TZ 4
#define TY 4
#define TXW 64
#define SZ (TZ + 2)             // 6
#define SY (TY + 2)             // 6
#define SX (TXW + 2)            // 66
#define SVOX (SZ * SY * SX)     // 2376 -> 3 planes = 28.5 KB -> 5 blocks/CU

__device__ __forceinline__ float clampc(float v) {
    return fminf(fmaxf(v, 0.0f), (float)(DD - 1));
}

struct CornerC {
    int z0, z1, y0, y1, x0, x1;
    float w000, w001, w010, w011, w100, w101, w110, w111;
};

__device__ __forceinline__ CornerC corner_setup_c(float cz, float cy, float cx) {
    float z0f = floorf(cz), y0f = floorf(cy), x0f = floorf(cx);
    float wz = cz - z0f, wy = cy - y0f, wx = cx - x0f;
    CornerC c;
    c.z0 = (int)z0f; c.y0 = (int)y0f; c.x0 = (int)x0f;
    c.z1 = min(c.z0 + 1, DD - 1);
    c.y1 = min(c.y0 + 1, DD - 1);
    c.x1 = min(c.x0 + 1, DD - 1);
    float omz = 1.0f - wz, omy = 1.0f - wy, omx = 1.0f - wx;
    c.w000 = omz * omy * omx; c.w001 = omz * omy * wx;
    c.w010 = omz * wy * omx;  c.w011 = omz * wy * wx;
    c.w100 = wz * omy * omx;  c.w101 = wz * omy * wx;
    c.w110 = wz * wy * omx;   c.w111 = wz * wy * wx;
    return c;
}

struct Corners {
    int i000, i001, i010, i011, i100, i101, i110, i111;
    float w000, w001, w010, w011, w100, w101, w110, w111;
};

__device__ __forceinline__ Corners corner_setup(float cz, float cy, float cx) {
    CornerC c = corner_setup_c(cz, cy, cx);
    Corners g;
    int zs0 = c.z0 << 14, zs1 = c.z1 << 14;
    int ys0 = c.y0 << 7,  ys1 = c.y1 << 7;
    g.i000 = zs0 + ys0 + c.x0; g.i001 = zs0 + ys0 + c.x1;
    g.i010 = zs0 + ys1 + c.x0; g.i011 = zs0 + ys1 + c.x1;
    g.i100 = zs1 + ys0 + c.x0; g.i101 = zs1 + ys0 + c.x1;
    g.i110 = zs1 + ys1 + c.x0; g.i111 = zs1 + ys1 + c.x1;
    g.w000 = c.w000; g.w001 = c.w001; g.w010 = c.w010; g.w011 = c.w011;
    g.w100 = c.w100; g.w101 = c.w101; g.w110 = c.w110; g.w111 = c.w111;
    return g;
}

__device__ __forceinline__ float3 trilerp4(const float4* __restrict__ src,
                                           const Corners& c, float3 base) {
    float4 v000 = src[c.i000], v001 = src[c.i001];
    float4 v010 = src[c.i010], v011 = src[c.i011];
    float4 v100 = src[c.i100], v101 = src[c.i101];
    float4 v110 = src[c.i110], v111 = src[c.i111];
    float3 r;
    r.x = base.x + c.w000*v000.x + c.w001*v001.x + c.w010*v010.x + c.w011*v011.x
                 + c.w100*v100.x + c.w101*v101.x + c.w110*v110.x + c.w111*v111.x;
    r.y = base.y + c.w000*v000.y + c.w001*v001.y + c.w010*v010.y + c.w011*v011.y
                 + c.w100*v100.y + c.w101*v101.y + c.w110*v110.y + c.w111*v111.y;
    r.z = base.z + c.w000*v000.z + c.w001*v001.z + c.w010*v010.z + c.w011*v011.z
                 + c.w100*v100.z + c.w101*v101.z + c.w110*v110.z + c.w111*v111.z;
    return r;
}

// ===========================================================================
// FAST PATH: high-occupancy halo-1 LDS steps
// PLANAR_SRC=true reads the raw planar dvf scaled by 2^-7 (pack fused away).
// ===========================================================================
template <bool PLANAR_SRC>
__global__ __launch_bounds__(256)
void step_lds_kernel(const float4* __restrict__ src4,
                     const float* __restrict__ srcp,
                     float4* __restrict__ dst) {
    __shared__ float sf0[SVOX];
    __shared__ float sf1[SVOX];
    __shared__ float sf2[SVOX];

    int bid = blockIdx.x;                  // 2048 = 2x * 32y * 32z tiles
    int X0 = (bid & 1) * TXW;
    int Y0 = ((bid >> 1) & 31) * TY;
    int Z0 = (bid >> 6) * TZ;
    int t = threadIdx.x;

    // ---- stage tile + halo1 (coords clamped at volume edges) ----
    for (int s = t; s < SVOX; s += 256) {
        int xp = s % SX;
        int r  = s / SX;
        int yp = r % SY;
        int zp = r / SY;
        int gz = min(max(Z0 - 1 + zp, 0), DD - 1);
        int gy = min(max(Y0 - 1 + yp, 0), DD - 1);
        int gx = min(max(X0 - 1 + xp, 0), DD - 1);
        int g  = (gz << 14) + (gy << 7) + gx;
        if (PLANAR_SRC) {
            sf0[s] = srcp[g] * SCALE;
            sf1[s] = srcp[g + NV] * SCALE;
            sf2[s] = srcp[g + 2 * NV] * SCALE;
        } else {
            float4 v = src4[g];
            sf0[s] = v.x; sf1[s] = v.y; sf2[s] = v.z;
        }
    }
    __syncthreads();

    int tx = t & (TXW - 1);                // wave = one full x-row
    int ty = t >> 6;                       // 0..3
    int x = X0 + tx, y = Y0 + ty;

    for (int lz = 0; lz < TZ; ++lz) {
        int z = Z0 + lz;
        int sown = ((lz + 1) * SY + (ty + 1)) * SX + (tx + 1);
        float d0 = sf0[sown], d1 = sf1[sown], d2 = sf2[sown];

        float cz = clampc((float)z + d0);
        float cy = clampc((float)y + d1);
        float cx = clampc((float)x + d2);
        CornerC c = corner_setup_c(cz, cy, cx);

        // staged global range: [Z0-1, Z0+TZ] x [Y0-1, Y0+TY] x [X0-1, X0+TXW]
        bool in_tile = (c.z0 >= Z0 - 1) & (c.z1 <= Z0 + TZ)
                     & (c.y0 >= Y0 - 1) & (c.y1 <= Y0 + TY)
                     & (c.x0 >= X0 - 1) & (c.x1 <= X0 + TXW);

        float r0, r1, r2;
        if (__builtin_expect(in_tile, 1)) {
            int lz0 = c.z0 - (Z0 - 1), lz1 = c.z1 - (Z0 - 1);
            int ly0 = c.y0 - (Y0 - 1), ly1 = c.y1 - (Y0 - 1);
            int lx0 = c.x0 - (X0 - 1), lx1 = c.x1 - (X0 - 1);
            int b00 = (lz0 * SY + ly0) * SX;
            int b01 = (lz0 * SY + ly1) * SX;
            int b10 = (lz1 * SY + ly0) * SX;
            int b11 = (lz1 * SY + ly1) * SX;
            int a000 = b00 + lx0, a001 = b00 + lx1;
            int a010 = b01 + lx0, a011 = b01 + lx1;
            int a100 = b10 + lx0, a101 = b10 + lx1;
            int a110 = b11 + lx0, a111 = b11 + lx1;
            r0 = c.w000*sf0[a000] + c.w001*sf0[a001] + c.w010*sf0[a010] + c.w011*sf0[a011]
               + c.w100*sf0[a100] + c.w101*sf0[a101] + c.w110*sf0[a110] + c.w111*sf0[a111];
            r1 = c.w000*sf1[a000] + c.w001*sf1[a001] + c.w010*sf1[a010] + c.w011*sf1[a011]
               + c.w100*sf1[a100] + c.w101*sf1[a101] + c.w110*sf1[a110] + c.w111*sf1[a111];
            r2 = c.w000*sf2[a000] + c.w001*sf2[a001] + c.w010*sf2[a010] + c.w011*sf2[a011]
               + c.w100*sf2[a100] + c.w101*sf2[a101] + c.w110*sf2[a110] + c.w111*sf2[a111];
        } else {
            // rare per-lane fallback: exact global gather (any input stays correct)
            int zs0 = c.z0 << 14, zs1 = c.z1 << 14;
            int ys0 = c.y0 << 7,  ys1 = c.y1 << 7;
            int a000 = zs0+ys0+c.x0, a001 = zs0+ys0+c.x1;
            int a010 = zs0+ys1+c.x0, a011 = zs0+ys1+c.x1;
            int a100 = zs1+ys0+c.x0, a101 = zs1+ys0+c.x1;
            int a110 = zs1+ys1+c.x0, a111 = zs1+ys1+c.x1;
            if (PLANAR_SRC) {
                r0 = SCALE*(c.w000*srcp[a000] + c.w001*srcp[a001] + c.w010*srcp[a010] + c.w011*srcp[a011]
                          + c.w100*srcp[a100] + c.w101*srcp[a101] + c.w110*srcp[a110] + c.w111*srcp[a111]);
                r1 = SCALE*(c.w000*srcp[a000+NV] + c.w001*srcp[a001+NV] + c.w010*srcp[a010+NV] + c.w011*srcp[a011+NV]
                          + c.w100*srcp[a100+NV] + c.w101*srcp[a101+NV] + c.w110*srcp[a110+NV] + c.w111*srcp[a111+NV]);
                r2 = SCALE*(c.w000*srcp[a000+2*NV] + c.w001*srcp[a001+2*NV] + c.w010*srcp[a010+2*NV] + c.w011*srcp[a011+2*NV]
                          + c.w100*srcp[a100+2*NV] + c.w101*srcp[a101+2*NV] + c.w110*srcp[a110+2*NV] + c.w111*srcp[a111+2*NV]);
            } else {
                float4 v000 = src4[a000], v001 = src4[a001];
                float4 v010 = src4[a010], v011 = src4[a011];
                float4 v100 = src4[a100], v101 = src4[a101];
                float4 v110 = src4[a110], v111 = src4[a111];
                r0 = c.w000*v000.x + c.w001*v001.x + c.w010*v010.x + c.w011*v011.x
                   + c.w100*v100.x + c.w101*v101.x + c.w110*v110.x + c.w111*v111.x;
                r1 = c.w000*v000.y + c.w001*v001.y + c.w010*v010.y + c.w011*v011.y
                   + c.w100*v100.y + c.w101*v101.y + c.w110*v110.y + c.w111*v111.y;
                r2 = c.w000*v000.z + c.w001*v001.z + c.w010*v010.z + c.w011*v011.z
                   + c.w100*v100.z + c.w101*v101.z + c.w110*v110.z + c.w111*v111.z;
            }
        }

        dst[(z << 14) + (y << 7) + x] = make_float4(d0 + r0, d1 + r1, d2 + r2, 0.0f);
    }
}

// step 7 fused with output warps AND dvf pass-through (unchanged control)
__global__ __launch_bounds__(256)
void step7_final4_kernel(const float4* __restrict__ src,
                         const float* __restrict__ mimg,
                         const float* __restrict__ mlab,
                         const float* __restrict__ dvf,
                         float* __restrict__ ddf_out,
                         float* __restrict__ pred_img,
                         float* __restrict__ pred_lab,
                         float* __restrict__ dvf_out) {
    int tid = blockIdx.x * blockDim.x + threadIdx.x;
    int x = tid & (DD - 1);
    int y = (tid >> 7) & (DD - 1);
    int z = tid >> 14;

    float4 s = src[tid];
    float dv0 = dvf[tid], dv1 = dvf[tid + NV], dv2 = dvf[tid + 2 * NV];

    Corners c = corner_setup(clampc((float)z + s.x),
                             clampc((float)y + s.y),
                             clampc((float)x + s.z));
    float3 r = trilerp4(src, c, make_float3(s.x, s.y, s.z));

    ddf_out[tid]          = r.x;
    ddf_out[tid + NV]     = r.y;
    ddf_out[tid + 2 * NV] = r.z;
    dvf_out[tid]          = dv0;
    dvf_out[tid + NV]     = dv1;
    dvf_out[tid + 2 * NV] = dv2;

    float cz = clampc((float)z + r.x);
    float cy = clampc((float)y + r.y);
    float cx = clampc((float)x + r.z);

    {   // bilinear warp of moving_image
        Corners g = corner_setup(cz, cy, cx);
        pred_img[tid] = g.w000*mimg[g.i000] + g.w001*mimg[g.i001]
                      + g.w010*mimg[g.i010] + g.w011*mimg[g.i011]
                      + g.w100*mimg[g.i100] + g.w101*mimg[g.i101]
                      + g.w110*mimg[g.i110] + g.w111*mimg[g.i111];
    }
    {   // nearest warp of moving_label (jnp.round = ties-to-even = rintf)
        int zi = (int)rintf(cz);
        int yi = (int)rintf(cy);
        int xi = (int)rintf(cx);
        pred_lab[tid] = mlab[(zi << 14) + (yi << 7) + xi];
    }
}

// ===========================================================================
// FALLBACK PATH (ws too small): proven float3 ping-pong inside d_out
// ===========================================================================

__device__ __forceinline__ void trilerp3i(const float* __restrict__ src,
                                          const Corners& c,
                                          float& r0, float& r1, float& r2) {
    const float* p000 = src + 3 * c.i000; const float* p001 = src + 3 * c.i001;
    const float* p010 = src + 3 * c.i010; const float* p011 = src + 3 * c.i011;
    const float* p100 = src + 3 * c.i100; const float* p101 = src + 3 * c.i101;
    const float* p110 = src + 3 * c.i110; const float* p111 = src + 3 * c.i111;
    r0 = c.w000*p000[0] + c.w001*p001[0] + c.w010*p010[0] + c.w011*p011[0]
       + c.w100*p100[0] + c.w101*p101[0] + c.w110*p110[0] + c.w111*p111[0];
    r1 = c.w000*p000[1] + c.w001*p001[1] + c.w010*p010[1] + c.w011*p011[1]
       + c.w100*p100[1] + c.w101*p101[1] + c.w110*p110[1] + c.w111*p111[1];
    r2 = c.w000*p000[2] + c.w001*p001[2] + c.w010*p010[2] + c.w011*p011[2]
       + c.w100*p100[2] + c.w101*p101[2] + c.w110*p110[2] + c.w111*p111[2];
}

__global__ __launch_bounds__(256)
void init3_kernel(const float* __restrict__ dvf, float* __restrict__ A) {
    int tid = blockIdx.x * blockDim.x + threadIdx.x;
    float* p = A + 3 * tid;
    p[0] = dvf[tid] * SCALE;
    p[1] = dvf[tid + NV] * SCALE;
    p[2] = dvf[tid + 2 * NV] * SCALE;
}

__global__ __launch_bounds__(256)
void step3_kernel(const float* __restrict__ src, float* __restrict__ dst) {
    int tid = blockIdx.x * blockDim.x + threadIdx.x;
    int x = tid & (DD - 1);
    int y = (tid >> 7) & (DD - 1);
    int z = tid >> 14;
    const float* s = src + 3 * tid;
    float d0 = s[0], d1 = s[1], d2 = s[2];
    Corners c = corner_setup(clampc((float)z + d0),
                             clampc((float)y + d1),
                             clampc((float)x + d2));
    float r0, r1, r2;
    trilerp3i(src, c, r0, r1, r2);
    float* p = dst + 3 * tid;
    p[0] = d0 + r0; p[1] = d1 + r1; p[2] = d2 + r2;
}

__global__ __launch_bounds__(256)
void step7_final3_kernel(const float* __restrict__ src,
                         const float* __restrict__ mimg,
                         const float* __restrict__ mlab,
                         const float* __restrict__ dvf,
                         float* __restrict__ ddf_out,
                         float* __restrict__ pred_img,
                         float* __restrict__ pred_lab,
                         float* __restrict__ dvf_out) {
    int tid = blockIdx.x * blockDim.x + threadIdx.x;
    int x = tid & (DD - 1);
    int y = (tid >> 7) & (DD - 1);
    int z = tid >> 14;
    const float* s = src + 3 * tid;
    float d0 = s[0], d1 = s[1], d2 = s[2];
    Corners c = corner_setup(clampc((float)z + d0),
                             clampc((float)y + d1),
                             clampc((float)x + d2));
    float r0, r1, r2;
    trilerp3i(src, c, r0, r1, r2);
    r0 += d0; r1 += d1; r2 += d2;
    ddf_out[tid]          = r0;
    ddf_out[tid + NV]     = r1;
    ddf_out[tid + 2 * NV] = r2;
    dvf_out[tid]          = dvf[tid];
    dvf_out[tid + NV]     = dvf[tid + NV];
    dvf_out[tid + 2 * NV] = dvf[tid + 2 * NV];
    float cz = clampc((float)z + r0);
    float cy = clampc((float)y + r1);
    float cx = clampc((float)x + r2);
    {
        Corners g = corner_setup(cz, cy, cx);
        pred_img[tid] = g.w000*mimg[g.i000] + g.w001*mimg[g.i001]
                      + g.w010*mimg[g.i010] + g.w011*mimg[g.i011]
                      + g.w100*mimg[g.i100] + g.w101*mimg[g.i101]
                      + g.w110*mimg[g.i110] + g.w111*mimg[g.i111];
    }
    {
        int zi = (int)rintf(cz);
        int yi = (int)rintf(cy);
        int xi = (int)rintf(cx);
        pred_lab[tid] = mlab[(zi << 14) + (yi << 7) + xi];
    }
}

// ===========================================================================

extern "C" void kernel_launch(void* const* d_in, const int* in_sizes, int n_in,
                              void* d_out, int out_size, void* d_ws, size_t ws_size,
                              hipStream_t stream) {
    const float* dvf  = (const float*)d_in[0];
    const float* mimg = (const float*)d_in[1];
    // d_in[2] = fixed_image: unused by the reference outputs
    const float* mlab = (const float*)d_in[3];

    float* out      = (float*)d_out;
    float* ddf_out  = out;              // slot 0: ddf  [3,D,H,W]
    float* pred_img = out + 3 * NV;     // slot 1
    float* pred_lab = out + 4 * NV;     // slot 2
    float* dvf_out  = out + 5 * NV;     // slot 3: dvf pass-through

    dim3 block(256);
    dim3 grid(NV / 256);                // 8192 blocks
    dim3 gridT(NV / (TZ * TY * TXW));   // 2048 tile blocks

    if (ws_size >= (size_t)NV * 4 * sizeof(float)) {
        // FAST PATH. Ping-pong: P = d_ws (32 MB), Q = out[4NV, 8NV) (32 MB).
        // Q is dead before step7_final writes over it (lab slot + dvf slot).
        float4* P = (float4*)d_ws;
        float4* Q = (float4*)(out + 4 * NV);

        step_lds_kernel<true ><<<gridT, block, 0, stream>>>(nullptr, dvf, Q); // pack+step1
        step_lds_kernel<false><<<gridT, block, 0, stream>>>(Q, nullptr, P);   // step 2
        step_lds_kernel<false><<<gridT, block, 0, stream>>>(P, nullptr, Q);   // step 3
        step_lds_kernel<false><<<gridT, block, 0, stream>>>(Q, nullptr, P);   // step 4
        step_lds_kernel<false><<<gridT, block, 0, stream>>>(P, nullptr, Q);   // step 5
        step_lds_kernel<false><<<gridT, block, 0, stream>>>(Q, nullptr, P);   // step 6 -> P
        step7_final4_kernel<<<grid, block, 0, stream>>>(P, mimg, mlab, dvf,
                                                        ddf_out, pred_img,
                                                        pred_lab, dvf_out);
    } else {
        // FALLBACK: float3 ping-pong inside d_out.
        float* A = dvf_out;             // [5NV, 8NV)
        float* B = ddf_out;             // [0, 3NV)
        init3_kernel<<<grid, block, 0, stream>>>(dvf, A);
        step3_kernel<<<grid, block, 0, stream>>>(A, B);           // step 1
        step3_kernel<<<grid, block, 0, stream>>>(B, A);           // step 2
        step3_kernel<<<grid, block, 0, stream>>>(A, B);           // step 3
        step3_kernel<<<grid, block, 0, stream>>>(B, A);           // step 4
        step3_kernel<<<grid, block, 0, stream>>>(A, B);           // step 5
        step3_kernel<<<grid, block, 0, stream>>>(B, A);           // step 6 -> A
        step7_final3_kernel<<<grid, block, 0, stream>>>(A, mimg, mlab, dvf,
                                                        ddf_out, pred_img,
                                                        pred_lab, dvf_out);
    }
}